// Round 14
// baseline (240.365 us; speedup 1.0000x reference)
//
#include <hip/hip_runtime.h>
#include <hip/hip_bf16.h>

#define FEATSZ 2048
#define HIDSZ  1024
#define ATTSZ  512
#define BATCH  64
#define FEATN  512

typedef float  f32x4  __attribute__((ext_vector_type(4)));
typedef __bf16 bf16x8 __attribute__((ext_vector_type(8)));

__device__ __forceinline__ unsigned short f2bf(float f) {
    union { float f; unsigned int u; } x; x.f = f;
    unsigned int u = x.u;
    return (unsigned short)((u + 0x7fffu + ((u >> 16) & 1u)) >> 16);
}

// ---------------- K0a: h = key @ wh_w.T + wh_b  (64 x 512) ----------------
__global__ void k_h(const float* __restrict__ key, const float* __restrict__ wh_w,
                    const float* __restrict__ wh_b, float* __restrict__ h) {
    const int b = blockIdx.y;
    const int ac = blockIdx.x;
    const int t = threadIdx.x;         // 256
    const int lane = t & 63, wv = t >> 6;
    float k16[16];
    const float* kb = key + b * HIDSZ;
#pragma unroll
    for (int j = 0; j < 16; ++j) k16[j] = kb[lane + 64 * j];
#pragma unroll 1
    for (int i = 0; i < 16; ++i) {
        int a = ac * 64 + wv * 16 + i;
        const float* wr = wh_w + (size_t)a * HIDSZ;
        float s = 0.f;
#pragma unroll
        for (int j = 0; j < 16; ++j) s += k16[j] * wr[lane + 64 * j];
#pragma unroll
        for (int d = 32; d; d >>= 1) s += __shfl_xor(s, d);
        if (lane == 0) h[b * ATTSZ + a] = s + wh_b[a];
    }
}

// ------- K0b: convert wv_w (512x2048 f32) -> bf16 in MFMA-fragment order -------
// frag (kk, CF) = 1024B at (kk*32+CF)*1024; lane l holds 16B (8 bf16) at +l*16.
__global__ void k_wvcvt(const float* __restrict__ wv_w, unsigned short* __restrict__ wvb) {
    int idx = blockIdx.x * 256 + threadIdx.x;       // < 512*2048
    int a = idx >> 11, k = idx & 2047;
    int CF = a >> 4, c = a & 15, ks = k >> 5, kin = k & 31;
    int lane = c + ((kin >> 3) << 4);
    int dst = ((ks * 32 + CF) * 64 + lane) * 8 + (kin & 7);
    wvb[dst] = f2bf(wv_w[idx]);
}

// ---------------- K1: fused GEMM(feats, wv^T) + tanh·wa -> partial scores -------
// BARRIER-FREE (k_att_part-shaped): 256 blocks (64 batches x 4 col-quarters),
// 512 thr = 8 free-running waves. Wave owns 64 EXCLUSIVE rows x 128 cols
// (acc 4m x 8cf = 128 VGPR). A frags DIRECT from global (16x128B full segments
// per instr, zero LDS, zero barriers, rows wave-exclusive -> no redundancy);
// B from L2-resident frag-ordered wvb, named BX/BY 1-kk ping-pong. Epilogue is
// wave-local (shfl over low-4 lane bits) -> direct global store. No __syncthreads.
__global__ __launch_bounds__(512, 2) void k_scores(
        const float* __restrict__ feats, const unsigned short* __restrict__ wvb,
        const float* __restrict__ h, const float* __restrict__ wv_b,
        const float* __restrict__ wa, float* __restrict__ part_sc) {
    const int t = threadIdx.x, lane = t & 63, w = t >> 6;
    const int b = blockIdx.x;          // batch = 512-row group
    const int nc = blockIdx.y;         // col-quarter (128 cols)

    // ---- A: wave rows b*512 + w*64 + m*16 + (lane&15); k = kk*32 + (lane>>4)*8 + [0..8)
    const float* ga = feats + ((size_t)b * FEATN + w * 64 + (lane & 15)) * FEATSZ + (lane >> 4) * 8;
    // ---- B: frag (kk, nc*8+cf) at wvb + (kk*32 + nc*8 + cf)*512 + lane*8
    const unsigned short* wb = wvb + (size_t)(nc * 8) * 512 + lane * 8;

    f32x4 acc[4][8];
#pragma unroll
    for (int m = 0; m < 4; ++m)
#pragma unroll
        for (int cf = 0; cf < 8; ++cf) acc[m][cf] = (f32x4)0.0f;

    f32x4 fa[4], fb[4];                // A fp32 staging (per-m, 1-kk lookahead)
    bf16x8 BX[8], BY[8];               // B ping-pong (named)

    auto loadA = [&](int m, int kk) {
        const float* p = ga + (size_t)(m * 16) * FEATSZ + kk * 32;
        fa[m] = *(const f32x4*)p;
        fb[m] = *(const f32x4*)(p + 4);
    };
    auto loadBX = [&](int kk) {
#pragma unroll
        for (int cf = 0; cf < 8; ++cf)
            BX[cf] = *(const bf16x8*)(wb + (size_t)(kk * 32 + cf) * 512);
    };
    auto loadBY = [&](int kk) {
#pragma unroll
        for (int cf = 0; cf < 8; ++cf)
            BY[cf] = *(const bf16x8*)(wb + (size_t)(kk * 32 + cf) * 512);
    };

    // ---- prologue: A(0), BX(0)
#pragma unroll
    for (int m = 0; m < 4; ++m) loadA(m, 0);
    loadBX(0);

#pragma unroll 1
    for (int kk2 = 0; kk2 < 32; ++kk2) {
        const int kk = kk2 * 2;
        // ---- even: consume A(kk)+BX(kk); refill A->kk+1, BY->kk+1
        loadBY(kk + 1);
#pragma unroll
        for (int m = 0; m < 4; ++m) {
            bf16x8 af;
            af[0] = (__bf16)fa[m][0]; af[1] = (__bf16)fa[m][1];
            af[2] = (__bf16)fa[m][2]; af[3] = (__bf16)fa[m][3];
            af[4] = (__bf16)fb[m][0]; af[5] = (__bf16)fb[m][1];
            af[6] = (__bf16)fb[m][2]; af[7] = (__bf16)fb[m][3];
            loadA(m, kk + 1);
            __builtin_amdgcn_s_setprio(1);
#pragma unroll
            for (int cf = 0; cf < 8; ++cf)
                acc[m][cf] = __builtin_amdgcn_mfma_f32_16x16x32_bf16(af, BX[cf], acc[m][cf], 0, 0, 0);
            __builtin_amdgcn_s_setprio(0);
        }
        // ---- odd: consume A(kk+1)+BY(kk+1); refill A->kk+2, BX->kk+2
        const int kn = (kk + 2 < 64) ? kk + 2 : 63;
        loadBX(kn);
#pragma unroll
        for (int m = 0; m < 4; ++m) {
            bf16x8 af;
            af[0] = (__bf16)fa[m][0]; af[1] = (__bf16)fa[m][1];
            af[2] = (__bf16)fa[m][2]; af[3] = (__bf16)fa[m][3];
            af[4] = (__bf16)fb[m][0]; af[5] = (__bf16)fb[m][1];
            af[6] = (__bf16)fb[m][2]; af[7] = (__bf16)fb[m][3];
            loadA(m, kn);
            __builtin_amdgcn_s_setprio(1);
#pragma unroll
            for (int cf = 0; cf < 8; ++cf)
                acc[m][cf] = __builtin_amdgcn_mfma_f32_16x16x32_bf16(af, BY[cf], acc[m][cf], 0, 0, 0);
            __builtin_amdgcn_s_setprio(0);
        }
    }

    // ---- epilogue (wave-local, no barrier): partial score over 128 cols
    const int c16 = lane & 15, q4 = lane >> 4;
    float hreg[8], wreg[8];
#pragma unroll
    for (int cf = 0; cf < 8; ++cf) {
        int a = nc * 128 + cf * 16 + c16;
        hreg[cf] = h[b * ATTSZ + a] + wv_b[a];
        wreg[cf] = wa[a];
    }
    float pv[4][4];
#pragma unroll
    for (int m = 0; m < 4; ++m)
#pragma unroll
        for (int jr = 0; jr < 4; ++jr) pv[m][jr] = 0.f;
#pragma unroll
    for (int m = 0; m < 4; ++m)
#pragma unroll
        for (int cf = 0; cf < 8; ++cf)
#pragma unroll
            for (int jr = 0; jr < 4; ++jr)
                pv[m][jr] += tanhf(acc[m][cf][jr] + hreg[cf]) * wreg[cf];
#pragma unroll
    for (int m = 0; m < 4; ++m)
#pragma unroll
        for (int jr = 0; jr < 4; ++jr) {
            float v = pv[m][jr];
            v += __shfl_xor(v, 1); v += __shfl_xor(v, 2);
            v += __shfl_xor(v, 4); v += __shfl_xor(v, 8);
            pv[m][jr] = v;
        }
    if (c16 == 0) {
        float* dst = part_sc + (size_t)nc * (BATCH * FEATN) + b * FEATN + w * 64;
#pragma unroll
        for (int m = 0; m < 4; ++m)
#pragma unroll
            for (int jr = 0; jr < 4; ++jr)
                dst[m * 16 + q4 * 4 + jr] = pv[m][jr];
    }
}

// ---------------- K2: softmax over N=512 per batch (sums 4 col-partials) --------
__global__ void k_softmax(const float* __restrict__ part_sc, float* __restrict__ alpha) {
    __shared__ float red[16];
    const int b = blockIdx.x, t = threadIdx.x;     // 512 threads
    const int lane = t & 63, w = t >> 6;
    const int r = b * FEATN + t;
    float s = part_sc[r] + part_sc[BATCH * FEATN + r]
            + part_sc[2 * BATCH * FEATN + r] + part_sc[3 * BATCH * FEATN + r];
    float m = s;
#pragma unroll
    for (int d = 32; d; d >>= 1) m = fmaxf(m, __shfl_xor(m, d));
    if (lane == 0) red[w] = m;
    __syncthreads();
    if (t == 0) {
        float mm = red[0];
        for (int i = 1; i < 8; ++i) mm = fmaxf(mm, red[i]);
        red[8] = mm;
    }
    __syncthreads();
    float e = __expf(s - red[8]);
    float sum = e;
#pragma unroll
    for (int d = 32; d; d >>= 1) sum += __shfl_xor(sum, d);
    if (lane == 0) red[w] = sum;
    __syncthreads();
    if (t == 0) {
        float ss = 0.f;
        for (int i = 0; i < 8; ++i) ss += red[i];
        red[9] = 1.0f / ss;
    }
    __syncthreads();
    alpha[b * FEATN + t] = e * red[9];
}

// ---------------- K3a: partial att_feats over n-slices ----------------
__global__ void k_att_part(const float* __restrict__ feats, const float* __restrict__ alpha,
                           float* __restrict__ part) {
    const int b = blockIdx.x, fc = blockIdx.y, ns = blockIdx.z, t = threadIdx.x;
    const int f0 = fc * 1024 + t * 4;
    const float* fp = feats + (size_t)(b * FEATN + ns * 128) * FEATSZ + f0;
    const float* al = alpha + b * FEATN + ns * 128;
    float4 acc = {0.f, 0.f, 0.f, 0.f};
#pragma unroll 4
    for (int i = 0; i < 128; ++i) {
        float a = al[i];
        float4 v = *(const float4*)(fp + (size_t)i * FEATSZ);
        acc.x += a * v.x; acc.y += a * v.y; acc.z += a * v.z; acc.w += a * v.w;
    }
    *(float4*)(part + ((size_t)ns * BATCH + b) * FEATSZ + f0) = acc;
}

// ---------------- K3b: reduce 4 partials -> att_feats ----------------
__global__ void k_att_red(const float* __restrict__ part, float* __restrict__ out) {
    const int idx = (blockIdx.x * 256 + threadIdx.x) * 4;   // < 131072
    float4 s = *(const float4*)(part + idx);
#pragma unroll
    for (int z = 1; z < 4; ++z) {
        float4 v = *(const float4*)(part + (size_t)z * (BATCH * FEATSZ) + idx);
        s.x += v.x; s.y += v.y; s.z += v.z; s.w += v.w;
    }
    *(float4*)(out + idx) = s;
}

extern "C" void kernel_launch(void* const* d_in, const int* in_sizes, int n_in,
                              void* d_out, int out_size, void* d_ws, size_t ws_size,
                              hipStream_t stream) {
    const float* feats = (const float*)d_in[0];
    const float* key   = (const float*)d_in[1];
    const float* wh_w  = (const float*)d_in[2];
    const float* wh_b  = (const float*)d_in[3];
    const float* wv_w  = (const float*)d_in[4];
    const float* wv_b  = (const float*)d_in[5];
    const float* wa_w  = (const float*)d_in[6];

    float* out_att   = (float*)d_out;                 // 64*2048
    float* out_alpha = out_att + BATCH * FEATSZ;      // 64*512

    char* ws = (char*)d_ws;
    float* h            = (float*)(ws);               // 128 KB
    float* part_sc      = (float*)(ws + 131072);      // 4 x 128 KB = 512 KB
    unsigned short* wvb = (unsigned short*)(ws + 655360);  // 2 MB
    float* part         = (float*)(ws + 655360);      // 2 MB (reuses wvb after K1)

    hipLaunchKernelGGL(k_h,        dim3(8, 64),    dim3(256), 0, stream, key, wh_w, wh_b, h);
    hipLaunchKernelGGL(k_wvcvt,    dim3(4096),     dim3(256), 0, stream, wv_w, wvb);
    hipLaunchKernelGGL(k_scores,   dim3(64, 4),    dim3(512), 0, stream, feats, wvb, h, wv_b, wa_w, part_sc);
    hipLaunchKernelGGL(k_softmax,  dim3(64),       dim3(512), 0, stream, part_sc, out_alpha);
    hipLaunchKernelGGL(k_att_part, dim3(64, 2, 4), dim3(256), 0, stream, feats, out_alpha, part);
    hipLaunchKernelGGL(k_att_red,  dim3(128),      dim3(256), 0, stream, part, out_att);
}

// Round 16
// 184.703 us; speedup vs baseline: 1.3014x; 1.3014x over previous
//
#include <hip/hip_runtime.h>
#include <hip/hip_bf16.h>

#define FEATSZ 2048
#define HIDSZ  1024
#define ATTSZ  512
#define BATCH  64
#define FEATN  512

typedef float  f32x4  __attribute__((ext_vector_type(4)));
typedef __bf16 bf16x8 __attribute__((ext_vector_type(8)));

__device__ __forceinline__ unsigned short f2bf(float f) {
    union { float f; unsigned int u; } x; x.f = f;
    unsigned int u = x.u;
    return (unsigned short)((u + 0x7fffu + ((u >> 16) & 1u)) >> 16);
}

// ---------------- K0a: h = key @ wh_w.T + wh_b  (64 x 512) ----------------
__global__ void k_h(const float* __restrict__ key, const float* __restrict__ wh_w,
                    const float* __restrict__ wh_b, float* __restrict__ h) {
    const int b = blockIdx.y;
    const int ac = blockIdx.x;
    const int t = threadIdx.x;         // 256
    const int lane = t & 63, wv = t >> 6;
    float k16[16];
    const float* kb = key + b * HIDSZ;
#pragma unroll
    for (int j = 0; j < 16; ++j) k16[j] = kb[lane + 64 * j];
#pragma unroll 1
    for (int i = 0; i < 16; ++i) {
        int a = ac * 64 + wv * 16 + i;
        const float* wr = wh_w + (size_t)a * HIDSZ;
        float s = 0.f;
#pragma unroll
        for (int j = 0; j < 16; ++j) s += k16[j] * wr[lane + 64 * j];
#pragma unroll
        for (int d = 32; d; d >>= 1) s += __shfl_xor(s, d);
        if (lane == 0) h[b * ATTSZ + a] = s + wh_b[a];
    }
}

// ------- K0b: convert wv_w (512x2048 f32) -> bf16 in MFMA-fragment order -------
// frag (ks, CF) = 1024B at (ks*32+CF)*1024; lane l holds 16B (8 bf16) at +l*16.
__global__ void k_wvcvt(const float* __restrict__ wv_w, unsigned short* __restrict__ wvb) {
    int idx = blockIdx.x * 256 + threadIdx.x;       // < 512*2048
    int a = idx >> 11, k = idx & 2047;
    int CF = a >> 4, c = a & 15, ks = k >> 5, kin = k & 31;
    int lane = c + ((kin >> 3) << 4);
    int dst = ((ks * 32 + CF) * 64 + lane) * 8 + (kin & 7);
    wvb[dst] = f2bf(wv_w[idx]);
}

// ---------------- K1: fused GEMM(feats, wv^T) + tanh·wa -> partial scores -------
// m97-faithful structure, traffic-fixed: 1024 blocks, 256 thr = 4 waves (2x2),
// tile 128r x 128c (nc quarter), BK=32, 64 kiters -> 4 blocks/CU (40KB LDS,
// <=128 VGPR), 16 waves/CU from 4 INDEPENDENT barrier groups.
// XCD-colocation: all 4 nc-siblings of an mb land on ONE XCD, temporally
// adjacent -> A streamed from HBM once, siblings hit L2/L3.
// A: fp32 glb->reg (1-kiter cover) -> bf16 cvt ONCE -> swizzled ds_write, 2x8KB dbuf.
// B: global_load_lds from frag-ordered wvb into RING-3 (counted vmcnt(6): B
// prefetch never drained). One lgkm+vmcnt+barrier per kiter.
__global__ __launch_bounds__(256, 4) void k_scores(
        const float* __restrict__ feats, const unsigned short* __restrict__ wvb,
        const float* __restrict__ h, const float* __restrict__ wv_b,
        const float* __restrict__ wa, float* __restrict__ part_sc) {
    __shared__ __align__(16) char smem[40960];   // [0,16K): A dbuf 2x8K ; [16K,40K): B ring 3x8K

    const int t = threadIdx.x, lane = t & 63, w = t >> 6;   // 4 waves
    const int wm = w >> 1, wn = w & 1;
    const int xcd = blockIdx.x & 7, idx = blockIdx.x >> 3;
    const int mb = xcd * 32 + (idx >> 2);       // 0..255 (128-row group)
    const int nc = idx & 3;                     // col quarter
    const int m0 = mb * 128, b = mb >> 2;

    auto Abuf = [&](int i) -> char* { return smem + i * 8192; };          // i in {0,1}
    auto Bbuf = [&](int i) -> char* { return smem + 16384 + i * 8192; };  // i in {0,1,2}

    // ---- A staging: thread -> row sr = t>>1, half shf = t&1 (16 floats)
    const int sr = t >> 1, shf = t & 1;
    const float* gA = feats + (size_t)(m0 + sr) * FEATSZ + shf * 16;
    const int sx = (sr >> 1) & 3;
    const int wof0 = sr * 64 + (((shf * 2    ) ^ sx) * 16);
    const int wof1 = sr * 64 + (((shf * 2 + 1) ^ sx) * 16);

    // ---- B staging: wave w instr i covers 1KB chunk (w*2+i) of the 8KB tile
    const char* gBb = (const char*)wvb + (size_t)(nc * 8) * 1024 + (size_t)(w * 2) * 1024 + lane * 16;
    const int bdst = (w * 2) * 1024;            // wave-uniform LDS offset in B buf

    // ---- A frag read: m: row = wm*64 + m*16 + l15, chunk q = lane>>4, phys = q^((l15>>1)&3)
    const int l15 = lane & 15;
    const int abase = (wm * 64 + l15) * 64 + (((lane >> 4) ^ ((l15 >> 1) & 3)) * 16);
    // ---- B frag read: frag (wn*4+cf) at +cf*1024, per-lane +lane*16
    const int bbase = (wn * 4) * 1024 + lane * 16;

    f32x4 acc[4][4];
#pragma unroll
    for (int m = 0; m < 4; ++m)
#pragma unroll
        for (int cf = 0; cf < 4; ++cf) acc[m][cf] = (f32x4)0.0f;

    f32x4 GA0, GA1, GA2, GA3;

    auto gloadB = [&](char* dst, int kk) {
#pragma unroll
        for (int i = 0; i < 2; ++i)
            __builtin_amdgcn_global_load_lds(
                (const __attribute__((address_space(1))) void*)(gBb + (size_t)kk * 32768 + i * 1024),
                (__attribute__((address_space(3))) void*)(dst + bdst + i * 1024),
                16, 0, 0);
    };
    auto ldGA = [&](int kk) {
        const float* p = gA + kk * 32;
        GA0 = *(const f32x4*)p;       GA1 = *(const f32x4*)(p + 4);
        GA2 = *(const f32x4*)(p + 8); GA3 = *(const f32x4*)(p + 12);
    };
    auto cvtWrite = [&](char* dst) {
        bf16x8 v0, v1;
        v0[0] = (__bf16)GA0[0]; v0[1] = (__bf16)GA0[1]; v0[2] = (__bf16)GA0[2]; v0[3] = (__bf16)GA0[3];
        v0[4] = (__bf16)GA1[0]; v0[5] = (__bf16)GA1[1]; v0[6] = (__bf16)GA1[2]; v0[7] = (__bf16)GA1[3];
        v1[0] = (__bf16)GA2[0]; v1[1] = (__bf16)GA2[1]; v1[2] = (__bf16)GA2[2]; v1[3] = (__bf16)GA2[3];
        v1[4] = (__bf16)GA3[0]; v1[5] = (__bf16)GA3[1]; v1[6] = (__bf16)GA3[2]; v1[7] = (__bf16)GA3[3];
        *(bf16x8*)__builtin_assume_aligned(dst + wof0, 16) = v0;
        *(bf16x8*)__builtin_assume_aligned(dst + wof1, 16) = v1;
    };

    // ---- prologue: tile 0 -> Abuf(0) (direct), B(0)->Bbuf(0), B(1)->Bbuf(1); GA <- tile 1
    ldGA(0);
    gloadB(Bbuf(0), 0);
    gloadB(Bbuf(1), 1);
    cvtWrite(Abuf(0));              // compiler waits GA(0)
    ldGA(1);
    asm volatile("s_waitcnt vmcnt(6)" ::: "memory");   // B(0) landed; B(1)+GA(1) in flight
    asm volatile("s_waitcnt lgkmcnt(0)" ::: "memory");
    __builtin_amdgcn_s_barrier();
    __builtin_amdgcn_sched_barrier(0);

#pragma unroll 1
    for (int j = 0; j < 64; ++j) {
        const char* ar = Abuf(j & 1);
        char*       aw = Abuf((j & 1) ^ 1);
        const char* br = Bbuf(j % 3);
        // 1. B prefetch 2 ahead (ring-3, never drained)
        if (j < 62) gloadB(Bbuf((j + 2) % 3), j + 2);
        // 2. frags
        bf16x8 BF[4], AF[4];
#pragma unroll
        for (int cf = 0; cf < 4; ++cf)
            BF[cf] = *(const bf16x8*)__builtin_assume_aligned(br + bbase + cf * 1024, 16);
#pragma unroll
        for (int m = 0; m < 4; ++m)
            AF[m] = *(const bf16x8*)__builtin_assume_aligned(ar + abase + m * 1024, 16);
        // 3. MFMA 16
        __builtin_amdgcn_s_setprio(1);
#pragma unroll
        for (int m = 0; m < 4; ++m)
#pragma unroll
            for (int cf = 0; cf < 4; ++cf)
                acc[m][cf] = __builtin_amdgcn_mfma_f32_16x16x32_bf16(AF[m], BF[cf], acc[m][cf], 0, 0, 0);
        __builtin_amdgcn_s_setprio(0);
        // 4. write tile j+1 (GA loaded one kiter ago); load GA tile j+2
        if (j < 63) cvtWrite(aw);
        if (j < 62) ldGA(j + 2);
        // 5. counted waits + one barrier
        if (j < 62) asm volatile("s_waitcnt vmcnt(6)" ::: "memory");
        else        asm volatile("s_waitcnt vmcnt(0)" ::: "memory");
        asm volatile("s_waitcnt lgkmcnt(0)" ::: "memory");
        __builtin_amdgcn_s_barrier();
        __builtin_amdgcn_sched_barrier(0);
    }

    // ---- epilogue: partial score over this block's 128 cols (nc quarter)
    const int c16 = lane & 15, q4 = lane >> 4;
    float hreg[4], wreg[4];
#pragma unroll
    for (int cf = 0; cf < 4; ++cf) {
        int a = nc * 128 + wn * 64 + cf * 16 + c16;
        hreg[cf] = h[b * ATTSZ + a] + wv_b[a];
        wreg[cf] = wa[a];
    }
    float pv[4][4];
#pragma unroll
    for (int m = 0; m < 4; ++m)
#pragma unroll
        for (int jr = 0; jr < 4; ++jr) pv[m][jr] = 0.f;
#pragma unroll
    for (int m = 0; m < 4; ++m)
#pragma unroll
        for (int cf = 0; cf < 4; ++cf)
#pragma unroll
            for (int jr = 0; jr < 4; ++jr)
                pv[m][jr] += tanhf(acc[m][cf][jr] + hreg[cf]) * wreg[cf];
#pragma unroll
    for (int m = 0; m < 4; ++m)
#pragma unroll
        for (int jr = 0; jr < 4; ++jr) {
            float v = pv[m][jr];
            v += __shfl_xor(v, 1); v += __shfl_xor(v, 2);
            v += __shfl_xor(v, 4); v += __shfl_xor(v, 8);
            pv[m][jr] = v;
        }
    float* scp = (float*)smem;      // alias (loop ended with barrier)
    __builtin_amdgcn_s_barrier();
    if (c16 == 0) {
#pragma unroll
        for (int m = 0; m < 4; ++m)
#pragma unroll
            for (int jr = 0; jr < 4; ++jr)
                scp[wn * 128 + wm * 64 + m * 16 + q4 * 4 + jr] = pv[m][jr];
    }
    __syncthreads();
    if (t < 128)
        part_sc[(size_t)nc * (BATCH * FEATN) + m0 + t] = scp[t] + scp[128 + t];
}

// ---------------- K2: softmax over N=512 per batch (sums 4 col-partials) --------
__global__ void k_softmax(const float* __restrict__ part_sc, float* __restrict__ alpha) {
    __shared__ float red[16];
    const int b = blockIdx.x, t = threadIdx.x;     // 512 threads
    const int lane = t & 63, w = t >> 6;
    const int r = b * FEATN + t;
    float s = part_sc[r] + part_sc[BATCH * FEATN + r]
            + part_sc[2 * BATCH * FEATN + r] + part_sc[3 * BATCH * FEATN + r];
    float m = s;
#pragma unroll
    for (int d = 32; d; d >>= 1) m = fmaxf(m, __shfl_xor(m, d));
    if (lane == 0) red[w] = m;
    __syncthreads();
    if (t == 0) {
        float mm = red[0];
        for (int i = 1; i < 8; ++i) mm = fmaxf(mm, red[i]);
        red[8] = mm;
    }
    __syncthreads();
    float e = __expf(s - red[8]);
    float sum = e;
#pragma unroll
    for (int d = 32; d; d >>= 1) sum += __shfl_xor(sum, d);
    if (lane == 0) red[w] = sum;
    __syncthreads();
    if (t == 0) {
        float ss = 0.f;
        for (int i = 0; i < 8; ++i) ss += red[i];
        red[9] = 1.0f / ss;
    }
    __syncthreads();
    alpha[b * FEATN + t] = e * red[9];
}

// ---------------- K3a: partial att_feats over n-slices ----------------
__global__ void k_att_part(const float* __restrict__ feats, const float* __restrict__ alpha,
                           float* __restrict__ part) {
    const int b = blockIdx.x, fc = blockIdx.y, ns = blockIdx.z, t = threadIdx.x;
    const int f0 = fc * 1024 + t * 4;
    const float* fp = feats + (size_t)(b * FEATN + ns * 128) * FEATSZ + f0;
    const float* al = alpha + b * FEATN + ns * 128;
    float4 acc = {0.f, 0.f, 0.f, 0.f};
#pragma unroll 4
    for (int i = 0; i < 128; ++i) {
        float a = al[i];
        float4 v = *(const float4*)(fp + (size_t)i * FEATSZ);
        acc.x += a * v.x; acc.y += a * v.y; acc.z += a * v.z; acc.w += a * v.w;
    }
    *(float4*)(part + ((size_t)ns * BATCH + b) * FEATSZ + f0) = acc;
}

// ---------------- K3b: reduce 4 partials -> att_feats ----------------
__global__ void k_att_red(const float* __restrict__ part, float* __restrict__ out) {
    const int idx = (blockIdx.x * 256 + threadIdx.x) * 4;   // < 131072
    float4 s = *(const float4*)(part + idx);
#pragma unroll
    for (int z = 1; z < 4; ++z) {
        float4 v = *(const float4*)(part + (size_t)z * (BATCH * FEATSZ) + idx);
        s.x += v.x; s.y += v.y; s.z += v.z; s.w += v.w;
    }
    *(float4*)(out + idx) = s;
}

extern "C" void kernel_launch(void* const* d_in, const int* in_sizes, int n_in,
                              void* d_out, int out_size, void* d_ws, size_t ws_size,
                              hipStream_t stream) {
    const float* feats = (const float*)d_in[0];
    const float* key   = (const float*)d_in[1];
    const float* wh_w  = (const float*)d_in[2];
    const float* wh_b  = (const float*)d_in[3];
    const float* wv_w  = (const float*)d_in[4];
    const float* wv_b  = (const float*)d_in[5];
    const float* wa_w  = (const float*)d_in[6];

    float* out_att   = (float*)d_out;                 // 64*2048
    float* out_alpha = out_att + BATCH * FEATSZ;      // 64*512

    char* ws = (char*)d_ws;
    float* h            = (float*)(ws);               // 128 KB
    float* part_sc      = (float*)(ws + 131072);      // 4 x 128 KB = 512 KB
    unsigned short* wvb = (unsigned short*)(ws + 655360);  // 2 MB
    float* part         = (float*)(ws + 655360);      // 2 MB (reuses wvb after K1)

    hipLaunchKernelGGL(k_h,        dim3(8, 64),    dim3(256), 0, stream, key, wh_w, wh_b, h);
    hipLaunchKernelGGL(k_wvcvt,    dim3(4096),     dim3(256), 0, stream, wv_w, wvb);
    hipLaunchKernelGGL(k_scores,   dim3(1024),     dim3(256), 0, stream, feats, wvb, h, wv_b, wa_w, part_sc);
    hipLaunchKernelGGL(k_softmax,  dim3(64),       dim3(512), 0, stream, part_sc, out_alpha);
    hipLaunchKernelGGL(k_att_part, dim3(64, 2, 4), dim3(256), 0, stream, feats, out_alpha, part);
    hipLaunchKernelGGL(k_att_red,  dim3(128),      dim3(256), 0, stream, part, out_att);
}